// Round 14
// baseline (1719.450 us; speedup 1.0000x reference)
//
#include <hip/hip_runtime.h>
#include <cstdint>
#include <cstddef>

#define SEQ 32768
#define DIM 1024
#define HID 128
#define KMAXV 103   // int(0.1*1024)+1

using f4 = __attribute__((ext_vector_type(4))) float;
using f2 = __attribute__((ext_vector_type(2))) float;

// ---------------------------------------------------------------------------
// Kernel A: per-block partial column sums of x (f64, deterministic order).
// ---------------------------------------------------------------------------
__global__ __launch_bounds__(256) void pool_partial(const float* __restrict__ x,
                                                    double* __restrict__ part) {
    const int b = blockIdx.x;
    const int t = threadIdx.x;
    const int r0 = b * 128;
    double s0 = 0.0, s1 = 0.0, s2 = 0.0, s3 = 0.0;
    for (int r = 0; r < 128; ++r) {
        const float* row = x + (size_t)(r0 + r) * DIM;
        s0 += (double)row[t];
        s1 += (double)row[t + 256];
        s2 += (double)row[t + 512];
        s3 += (double)row[t + 768];
    }
    double* p = part + (size_t)b * DIM;
    p[t] = s0; p[t + 256] = s1; p[t + 512] = s2; p[t + 768] = s3;
}

// ---------------------------------------------------------------------------
// Kernel B: finish pooling, complexity net (exact erf GELU, sigmoid), k.
// ---------------------------------------------------------------------------
__global__ __launch_bounds__(1024) void tiny_net(const double* __restrict__ part,
                                                 const float* __restrict__ w1,
                                                 const float* __restrict__ b1,
                                                 const float* __restrict__ w2,
                                                 const float* __restrict__ b2,
                                                 float* __restrict__ out_scalars,
                                                 int* __restrict__ kout) {
    __shared__ double pooled[DIM];
    __shared__ double hidv[HID];
    const int t = threadIdx.x;

    double s = 0.0;
    for (int b = 0; b < 256; ++b) s += part[(size_t)b * DIM + t];
    pooled[t] = s / (double)SEQ;
    __syncthreads();

    if (t < HID) {
        double h = (double)b1[t];
        for (int d = 0; d < DIM; ++d) h += pooled[d] * (double)w1[d * HID + t];
        h = 0.5 * h * (1.0 + erf(h * 0.70710678118654752440));
        hidv[t] = h;
    }
    __syncthreads();

    if (t == 0) {
        double z = (double)b2[0];
        for (int j = 0; j < HID; ++j) z += hidv[j] * (double)w2[j];
        double c = 1.0 / (1.0 + exp(-z));
        double ar = 0.01 + 0.09 * c;
        int k = (int)(ar * (double)DIM);  // trunc
        if (k < 1) k = 1;
        if (k > KMAXV) k = KMAXV;
        out_scalars[0] = (float)c;
        out_scalars[1] = (float)ar;
        out_scalars[2] = (float)k;
        *kout = k;
    }
}

// ---------------------------------------------------------------------------
// GEMM with numpy/OpenBLAS f32 semantics — NUMERICS FROZEN: per element,
// sequential-k IEEE fmaf within panels {384,320,320}, panel sums added in
// order ((P1+P2)+P3). Per-element op order identical to rounds 2..13.
//
// R13 falsified the SMEM-latency theory (full-step prefetch changed nothing)
// -> the scalar K$ port is BANDWIDTH-saturated: every wave of every resident
// block issues the same x s_loads and each consumes port cycles. R14 moves x
// to the VECTOR path: per-lane loads at a wave-uniform address = one L1
// transaction broadcast into VGPRs; v_fma_f32 all-VGPR. Zero scalar traffic,
// zero LDS. Double-buffered x (64 VGPR) + w (32) + acc (32) ~ 138 regs;
// amdgpu_waves_per_eu(2,4) is the correct allocator knob (launch_bounds 2nd
// arg was ignored in R5) -> ~3 waves/SIMD with full dbuf ILP.
// No pk_fma: R11==R13 showed packed f32 has identical FMA throughput.
// ---------------------------------------------------------------------------
#define BM 16
#define CBLOCK 512

// one 4-k FMA block for 8 rows x 4 cols, strict k-ascending per element
__device__ __forceinline__ void fma_block(const f4 xq[8], const f4 wq[4],
                                          f4 acc[8]) {
#pragma unroll
    for (int m = 0; m < 8; ++m) {
#pragma unroll
        for (int j = 0; j < 4; ++j) {
            float a = acc[m][j];
            a = fmaf(xq[m][0], wq[0][j], a);   // k+0
            a = fmaf(xq[m][1], wq[1][j], a);   // k+1
            a = fmaf(xq[m][2], wq[2][j], a);   // k+2
            a = fmaf(xq[m][3], wq[3][j], a);   // k+3
            acc[m][j] = a;
        }
    }
}

template<int K0, int K1>
__device__ __forceinline__ void panel_accv(const float* __restrict__ xbase,
                                           const float* __restrict__ wbase,
                                           f4 acc[8]) {
#pragma unroll
    for (int m = 0; m < 8; ++m) { acc[m][0] = 0.0f; acc[m][1] = 0.0f; acc[m][2] = 0.0f; acc[m][3] = 0.0f; }

    f4 xA[8], xB[8], wA[4], wB[4];

    // preload step K0 (buffer A) — x at wave-uniform addresses (L1 broadcast)
#pragma unroll
    for (int m = 0; m < 8; ++m) xA[m] = *(const f4*)(xbase + m * DIM + K0);
#pragma unroll
    for (int j = 0; j < 4; ++j) wA[j] = *(const f4*)(wbase + (size_t)(K0 + j) * DIM);

    for (int kk0 = K0; kk0 < K1; kk0 += 8) {
        // issue buffer B (step kk0+4; PK % 8 == 0 so always in range)
#pragma unroll
        for (int m = 0; m < 8; ++m) xB[m] = *(const f4*)(xbase + m * DIM + kk0 + 4);
#pragma unroll
        for (int j = 0; j < 4; ++j) wB[j] = *(const f4*)(wbase + (size_t)(kk0 + 4 + j) * DIM);

        fma_block(xA, wA, acc);                           // k = kk0..kk0+3

        // issue buffer A for next iteration (tail: dummy reload of K0)
        const int kn = (kk0 + 8 < K1) ? kk0 + 8 : K0;
#pragma unroll
        for (int m = 0; m < 8; ++m) xA[m] = *(const f4*)(xbase + m * DIM + kn);
#pragma unroll
        for (int j = 0; j < 4; ++j) wA[j] = *(const f4*)(wbase + (size_t)(kn + j) * DIM);

        fma_block(xB, wB, acc);                           // k = kk0+4..kk0+7
    }
}

__global__ __launch_bounds__(CBLOCK)
__attribute__((amdgpu_waves_per_eu(2, 4)))
void panel1_kernel(const float* __restrict__ x,
                   const float* __restrict__ wg,
                   float* __restrict__ out) {
    const int t = threadIdx.x;
    const int c4 = (t & 255) << 2;
    const int rg = t >> 8;
    const int row0 = blockIdx.x * BM + rg * 8;

    f4 acc[8];
    panel_accv<0, 384>(x + (size_t)row0 * DIM, wg + c4, acc);

#pragma unroll
    for (int m = 0; m < 8; ++m)
        *(f4*)(out + (size_t)(row0 + m) * DIM + c4) = acc[m];
}

__global__ __launch_bounds__(CBLOCK)
__attribute__((amdgpu_waves_per_eu(2, 4)))
void panel2_kernel(const float* __restrict__ x,
                   const float* __restrict__ wg,
                   float* __restrict__ out) {
    const int t = threadIdx.x;
    const int c4 = (t & 255) << 2;
    const int rg = t >> 8;
    const int row0 = blockIdx.x * BM + rg * 8;

    f4 acc[8];
    panel_accv<384, 704>(x + (size_t)row0 * DIM, wg + c4, acc);

#pragma unroll
    for (int m = 0; m < 8; ++m) {
        float* op = out + (size_t)(row0 + m) * DIM + c4;
        f4 d = *(const f4*)op;
#pragma unroll
        for (int j = 0; j < 4; ++j) d[j] = d[j] + acc[m][j];   // fl(P1+P2)
        *(f4*)op = d;
    }
}

__global__ __launch_bounds__(CBLOCK)
__attribute__((amdgpu_waves_per_eu(2, 4)))
void panel3_kernel(const float* __restrict__ x,
                   const float* __restrict__ wg,
                   const float* __restrict__ bg,
                   const float* __restrict__ rm,
                   const float* __restrict__ rv,
                   const int* __restrict__ kptr,
                   float* __restrict__ out) {
    __shared__ float lbuf[8 * DIM];

    const int t = threadIdx.x;
    const int c4 = (t & 255) << 2;
    const int rg = t >> 8;
    const int row0 = blockIdx.x * BM + rg * 8;

    f4 acc[8];
    panel_accv<704, 1024>(x + (size_t)row0 * DIM, wg + c4, acc);

    f4 dot[8];
#pragma unroll
    for (int m = 0; m < 8; ++m) {
        const f4 d = *(const f4*)(out + (size_t)(row0 + m) * DIM + c4);
#pragma unroll
        for (int j = 0; j < 4; ++j) dot[m][j] = d[j] + acc[m][j];  // fl((P1+P2)+P3)
    }

    // f32 epilogue, op-for-op as numpy
    const f4 vbg = *(const f4*)(bg + c4);
    const f4 vrm = *(const f4*)(rm + c4);
    const f4 vrv = *(const f4*)(rv + c4);
    f4 vden;
#pragma unroll
    for (int j = 0; j < 4; ++j) vden[j] = sqrtf(vrv[j]) + 1e-6f;

    f4 imp[8];
#pragma unroll
    for (int m = 0; m < 8; ++m)
#pragma unroll
        for (int j = 0; j < 4; ++j)
            imp[m][j] = (fabsf(dot[m][j] + vbg[j]) - vrm[j]) / vden[j];

    int kval = *kptr;
    if (kval < 1) kval = 1;
    if (kval > DIM) kval = DIM;

    float (*selbuf)[DIM] = (float (*)[DIM])lbuf;

    // two chunks of 8 rows; one wave per row does exact kth-largest selection
    for (int ch = 0; ch < 2; ++ch) {
        __syncthreads();
        if (rg == ch) {
#pragma unroll
            for (int m = 0; m < 8; ++m)
                *(f4*)(&selbuf[m][c4]) = imp[m];
        }
        __syncthreads();

        const int w = t >> 6;    // wave id 0..7 -> row within chunk
        const int l = t & 63;    // lane
        const size_t srow = (size_t)(blockIdx.x * BM + ch * 8 + w);

        // monotonic u32 keys for descending f32 order
        unsigned keys[16];
#pragma unroll
        for (int j = 0; j < 4; ++j) {
            const f4 v = *(const f4*)(&selbuf[w][4 * l + 256 * j]);
#pragma unroll
            for (int i = 0; i < 4; ++i) {
                const unsigned u = __float_as_uint(v[i]);
                keys[j * 4 + i] = (u & 0x80000000u) ? ~u : (u | 0x80000000u);
            }
        }

        // bitwise search for the kth-largest key: largest T with count(>=T) >= k
        unsigned pref = 0u;
        for (int b = 31; b >= 0; --b) {
            const unsigned tt = pref | (1u << b);
            int cnt = 0;
#pragma unroll
            for (int j = 0; j < 16; ++j) cnt += (keys[j] >= tt) ? 1 : 0;
#pragma unroll
            for (int off = 32; off >= 1; off >>= 1) cnt += __shfl_xor(cnt, off, 64);
            if (cnt >= kval) pref = tt;
        }

        // mask = importance >= kth (tie-inclusive); coalesced float4 out
        const float* xr = x + srow * DIM;
        float* orow = out + srow * DIM;
#pragma unroll
        for (int j = 0; j < 4; ++j) {
            const f4 xv = *(const f4*)(xr + 4 * l + 256 * j);
            f4 o;
#pragma unroll
            for (int i = 0; i < 4; ++i) o[i] = (keys[j * 4 + i] >= pref) ? xv[i] : 0.0f;
            *(f4*)(orow + 4 * l + 256 * j) = o;
        }
    }
}

// ---------------------------------------------------------------------------
extern "C" void kernel_launch(void* const* d_in, const int* in_sizes, int n_in,
                              void* d_out, int out_size, void* d_ws, size_t ws_size,
                              hipStream_t stream) {
    const float* x  = (const float*)d_in[0];
    const float* w1 = (const float*)d_in[1];
    const float* b1 = (const float*)d_in[2];
    const float* w2 = (const float*)d_in[3];
    const float* b2 = (const float*)d_in[4];
    const float* wg = (const float*)d_in[5];
    const float* bg = (const float*)d_in[6];
    const float* rm = (const float*)d_in[7];
    const float* rv = (const float*)d_in[8];
    float* out = (float*)d_out;

    double* part = (double*)d_ws;                                  // 256*1024 f64 = 2 MB
    int* kptr = (int*)((char*)d_ws + (size_t)256 * DIM * sizeof(double));

    pool_partial<<<256, 256, 0, stream>>>(x, part);
    tiny_net<<<1, 1024, 0, stream>>>(part, w1, b1, w2, b2,
                                     out + (size_t)SEQ * DIM, kptr);
    panel1_kernel<<<SEQ / BM, CBLOCK, 0, stream>>>(x, wg, out);
    panel2_kernel<<<SEQ / BM, CBLOCK, 0, stream>>>(x, wg, out);
    panel3_kernel<<<SEQ / BM, CBLOCK, 0, stream>>>(x, wg, bg, rm, rv, kptr, out);
}

// Round 15
// 1052.393 us; speedup vs baseline: 1.6338x; 1.6338x over previous
//
#include <hip/hip_runtime.h>
#include <cstdint>
#include <cstddef>

#define SEQ 32768
#define DIM 1024
#define HID 128
#define KMAXV 103   // int(0.1*1024)+1

using f8 = __attribute__((ext_vector_type(8))) float;
using f4 = __attribute__((ext_vector_type(4))) float;
using f2 = __attribute__((ext_vector_type(2))) float;

// ---------------------------------------------------------------------------
// Kernel A: per-block partial column sums of x (f64, deterministic order).
// ---------------------------------------------------------------------------
__global__ __launch_bounds__(256) void pool_partial(const float* __restrict__ x,
                                                    double* __restrict__ part) {
    const int b = blockIdx.x;
    const int t = threadIdx.x;
    const int r0 = b * 128;
    double s0 = 0.0, s1 = 0.0, s2 = 0.0, s3 = 0.0;
    for (int r = 0; r < 128; ++r) {
        const float* row = x + (size_t)(r0 + r) * DIM;
        s0 += (double)row[t];
        s1 += (double)row[t + 256];
        s2 += (double)row[t + 512];
        s3 += (double)row[t + 768];
    }
    double* p = part + (size_t)b * DIM;
    p[t] = s0; p[t + 256] = s1; p[t + 512] = s2; p[t + 768] = s3;
}

// ---------------------------------------------------------------------------
// Kernel B: finish pooling, complexity net (exact erf GELU, sigmoid), k.
// ---------------------------------------------------------------------------
__global__ __launch_bounds__(1024) void tiny_net(const double* __restrict__ part,
                                                 const float* __restrict__ w1,
                                                 const float* __restrict__ b1,
                                                 const float* __restrict__ w2,
                                                 const float* __restrict__ b2,
                                                 float* __restrict__ out_scalars,
                                                 int* __restrict__ kout) {
    __shared__ double pooled[DIM];
    __shared__ double hidv[HID];
    const int t = threadIdx.x;

    double s = 0.0;
    for (int b = 0; b < 256; ++b) s += part[(size_t)b * DIM + t];
    pooled[t] = s / (double)SEQ;
    __syncthreads();

    if (t < HID) {
        double h = (double)b1[t];
        for (int d = 0; d < DIM; ++d) h += pooled[d] * (double)w1[d * HID + t];
        h = 0.5 * h * (1.0 + erf(h * 0.70710678118654752440));
        hidv[t] = h;
    }
    __syncthreads();

    if (t == 0) {
        double z = (double)b2[0];
        for (int j = 0; j < HID; ++j) z += hidv[j] * (double)w2[j];
        double c = 1.0 / (1.0 + exp(-z));
        double ar = 0.01 + 0.09 * c;
        int k = (int)(ar * (double)DIM);  // trunc
        if (k < 1) k = 1;
        if (k > KMAXV) k = KMAXV;
        out_scalars[0] = (float)c;
        out_scalars[1] = (float)ar;
        out_scalars[2] = (float)k;
        *kout = k;
    }
}

// ---------------------------------------------------------------------------
// GEMM with numpy/OpenBLAS f32 semantics — NUMERICS FROZEN: per element,
// sequential-k IEEE fma within panels {384,320,320}, panel sums added in
// order ((P1+P2)+P3). v_pk_fma_f32 = independent IEEE fma per half; each
// column chain keeps the exact per-element op order of rounds 2..14.
//
// R13/R14 lesson: SMEM returns out-of-order -> only lgkmcnt(0) drains ->
// software pipelining s_loads is impossible (compiler collapses the buffers,
// VGPR 44 proof). Remaining lever is AMORTIZATION: fewest, widest SMEM
// batches per FMA block. R15: x via s_load_dwordx8 (1 op per row per 8 k;
// R10 dwordx2->R11 dwordx4 gave ~9%, this halves ops again and gives each
// drain 256 cyc of pk_fma cover). Column map = R10's (2 cols/thread, 512
// threads cover all 1024 cols, no rg duplication -> wq L2 traffic minimal).
// m-loop split into 8-row halves caps live x-SGPRs at 64 (<102 budget).
// ---------------------------------------------------------------------------
#define BM 16
#define CBLOCK 512

// 8 sequential-k pk_fma for one row from one f8 x batch (k..k+7)
__device__ __forceinline__ void fma_row8(const f8& x8, const f2 w[8], f2& acc) {
    const f2 x01 = __builtin_shufflevector(x8, x8, 0, 1);
    const f2 x23 = __builtin_shufflevector(x8, x8, 2, 3);
    const f2 x45 = __builtin_shufflevector(x8, x8, 4, 5);
    const f2 x67 = __builtin_shufflevector(x8, x8, 6, 7);
    asm("v_pk_fma_f32 %0, %1, %2, %0 op_sel:[0,0,0] op_sel_hi:[0,1,1]"
        : "+v"(acc) : "s"(x01), "v"(w[0]));   // k+0
    asm("v_pk_fma_f32 %0, %1, %2, %0 op_sel:[1,0,0] op_sel_hi:[1,1,1]"
        : "+v"(acc) : "s"(x01), "v"(w[1]));   // k+1
    asm("v_pk_fma_f32 %0, %1, %2, %0 op_sel:[0,0,0] op_sel_hi:[0,1,1]"
        : "+v"(acc) : "s"(x23), "v"(w[2]));   // k+2
    asm("v_pk_fma_f32 %0, %1, %2, %0 op_sel:[1,0,0] op_sel_hi:[1,1,1]"
        : "+v"(acc) : "s"(x23), "v"(w[3]));   // k+3
    asm("v_pk_fma_f32 %0, %1, %2, %0 op_sel:[0,0,0] op_sel_hi:[0,1,1]"
        : "+v"(acc) : "s"(x45), "v"(w[4]));   // k+4
    asm("v_pk_fma_f32 %0, %1, %2, %0 op_sel:[1,0,0] op_sel_hi:[1,1,1]"
        : "+v"(acc) : "s"(x45), "v"(w[5]));   // k+5
    asm("v_pk_fma_f32 %0, %1, %2, %0 op_sel:[0,0,0] op_sel_hi:[0,1,1]"
        : "+v"(acc) : "s"(x67), "v"(w[6]));   // k+6
    asm("v_pk_fma_f32 %0, %1, %2, %0 op_sel:[1,0,0] op_sel_hi:[1,1,1]"
        : "+v"(acc) : "s"(x67), "v"(w[7]));   // k+7
}

template<int K0, int K1>
__device__ __forceinline__ void panel_acc2(const float* __restrict__ xbase,
                                           const float* __restrict__ wbase,
                                           f2 acc[16]) {
#pragma unroll
    for (int m = 0; m < 16; ++m) { acc[m][0] = 0.0f; acc[m][1] = 0.0f; }

    for (int kk0 = K0; kk0 < K1; kk0 += 8) {
        // w for k = kk0..kk0+7 (per-thread f2, coalesced dwordx2)
        f2 w[8];
#pragma unroll
        for (int j = 0; j < 8; ++j)
            w[j] = *(const f2*)(wbase + (size_t)(kk0 + j) * DIM);

        // rows 0..7: one s_load_dwordx8 each (block-uniform address)
        {
            f8 xr[8];
#pragma unroll
            for (int m = 0; m < 8; ++m)
                xr[m] = *(const f8*)(xbase + m * DIM + kk0);
#pragma unroll
            for (int m = 0; m < 8; ++m)
                fma_row8(xr[m], w, acc[m]);
        }
        // rows 8..15
        {
            f8 xr[8];
#pragma unroll
            for (int m = 0; m < 8; ++m)
                xr[m] = *(const f8*)(xbase + (8 + m) * DIM + kk0);
#pragma unroll
            for (int m = 0; m < 8; ++m)
                fma_row8(xr[m], w, acc[8 + m]);
        }
    }
}

__global__ __launch_bounds__(CBLOCK) void panel1_kernel(const float* __restrict__ x,
                                                        const float* __restrict__ wg,
                                                        float* __restrict__ out) {
    const int t = threadIdx.x;
    const int c2 = t << 1;
    const int row0 = blockIdx.x * BM;

    f2 acc[16];
    panel_acc2<0, 384>(x + (size_t)row0 * DIM, wg + c2, acc);

#pragma unroll
    for (int m = 0; m < 16; ++m)
        *(f2*)(out + (size_t)(row0 + m) * DIM + c2) = acc[m];
}

__global__ __launch_bounds__(CBLOCK) void panel2_kernel(const float* __restrict__ x,
                                                        const float* __restrict__ wg,
                                                        float* __restrict__ out) {
    const int t = threadIdx.x;
    const int c2 = t << 1;
    const int row0 = blockIdx.x * BM;

    f2 acc[16];
    panel_acc2<384, 704>(x + (size_t)row0 * DIM, wg + c2, acc);

#pragma unroll
    for (int m = 0; m < 16; ++m) {
        float* op = out + (size_t)(row0 + m) * DIM + c2;
        f2 d = *(const f2*)op;
        d[0] = d[0] + acc[m][0];        // fl(P1+P2), plain f32 adds
        d[1] = d[1] + acc[m][1];
        *(f2*)op = d;
    }
}

__global__ __launch_bounds__(CBLOCK) void panel3_kernel(const float* __restrict__ x,
                                                        const float* __restrict__ wg,
                                                        const float* __restrict__ bg,
                                                        const float* __restrict__ rm,
                                                        const float* __restrict__ rv,
                                                        const int* __restrict__ kptr,
                                                        float* __restrict__ out) {
    __shared__ float lbuf[8 * DIM];

    const int t = threadIdx.x;
    const int c2 = t << 1;
    const int row0 = blockIdx.x * BM;

    f2 acc[16];
    panel_acc2<704, 1024>(x + (size_t)row0 * DIM, wg + c2, acc);

    float dot[16][2];
#pragma unroll
    for (int m = 0; m < 16; ++m) {
        const f2 d = *(const f2*)(out + (size_t)(row0 + m) * DIM + c2);
        dot[m][0] = d[0] + acc[m][0];   // fl((P1+P2)+P3)
        dot[m][1] = d[1] + acc[m][1];
    }

    // f32 epilogue, op-for-op as numpy
    const f2 vbg = *(const f2*)(bg + c2);
    const f2 vrm = *(const f2*)(rm + c2);
    const f2 vrv = *(const f2*)(rv + c2);
    f2 vden;
    vden[0] = sqrtf(vrv[0]) + 1e-6f;
    vden[1] = sqrtf(vrv[1]) + 1e-6f;

    f2 imp[16];
#pragma unroll
    for (int m = 0; m < 16; ++m) {
        imp[m][0] = (fabsf(dot[m][0] + vbg[0]) - vrm[0]) / vden[0];
        imp[m][1] = (fabsf(dot[m][1] + vbg[1]) - vrm[1]) / vden[1];
    }

    int kval = *kptr;
    if (kval < 1) kval = 1;
    if (kval > DIM) kval = DIM;

    float (*selbuf)[DIM] = (float (*)[DIM])lbuf;

    // two chunks of 8 rows; one wave per row does exact kth-largest selection
    for (int ch = 0; ch < 2; ++ch) {
        __syncthreads();
#pragma unroll
        for (int m = 0; m < 8; ++m)
            *(f2*)(&selbuf[m][c2]) = imp[ch * 8 + m];
        __syncthreads();

        const int w = t >> 6;    // wave id 0..7 -> row within chunk
        const int l = t & 63;    // lane
        const size_t srow = (size_t)(row0 + ch * 8 + w);

        // monotonic u32 keys for descending f32 order
        unsigned keys[16];
#pragma unroll
        for (int j = 0; j < 4; ++j) {
            const f4 v = *(const f4*)(&selbuf[w][4 * l + 256 * j]);
#pragma unroll
            for (int i = 0; i < 4; ++i) {
                const unsigned u = __float_as_uint(v[i]);
                keys[j * 4 + i] = (u & 0x80000000u) ? ~u : (u | 0x80000000u);
            }
        }

        // bitwise search for the kth-largest key: largest T with count(>=T) >= k
        unsigned pref = 0u;
        for (int b = 31; b >= 0; --b) {
            const unsigned tt = pref | (1u << b);
            int cnt = 0;
#pragma unroll
            for (int j = 0; j < 16; ++j) cnt += (keys[j] >= tt) ? 1 : 0;
#pragma unroll
            for (int off = 32; off >= 1; off >>= 1) cnt += __shfl_xor(cnt, off, 64);
            if (cnt >= kval) pref = tt;
        }

        // mask = importance >= kth (tie-inclusive); coalesced float4 out
        const float* xr = x + srow * DIM;
        float* orow = out + srow * DIM;
#pragma unroll
        for (int j = 0; j < 4; ++j) {
            const f4 xv = *(const f4*)(xr + 4 * l + 256 * j);
            f4 o;
#pragma unroll
            for (int i = 0; i < 4; ++i) o[i] = (keys[j * 4 + i] >= pref) ? xv[i] : 0.0f;
            *(f4*)(orow + 4 * l + 256 * j) = o;
        }
    }
}

// ---------------------------------------------------------------------------
extern "C" void kernel_launch(void* const* d_in, const int* in_sizes, int n_in,
                              void* d_out, int out_size, void* d_ws, size_t ws_size,
                              hipStream_t stream) {
    const float* x  = (const float*)d_in[0];
    const float* w1 = (const float*)d_in[1];
    const float* b1 = (const float*)d_in[2];
    const float* w2 = (const float*)d_in[3];
    const float* b2 = (const float*)d_in[4];
    const float* wg = (const float*)d_in[5];
    const float* bg = (const float*)d_in[6];
    const float* rm = (const float*)d_in[7];
    const float* rv = (const float*)d_in[8];
    float* out = (float*)d_out;

    double* part = (double*)d_ws;                                  // 256*1024 f64 = 2 MB
    int* kptr = (int*)((char*)d_ws + (size_t)256 * DIM * sizeof(double));

    pool_partial<<<256, 256, 0, stream>>>(x, part);
    tiny_net<<<1, 1024, 0, stream>>>(part, w1, b1, w2, b2,
                                     out + (size_t)SEQ * DIM, kptr);
    panel1_kernel<<<SEQ / BM, CBLOCK, 0, stream>>>(x, wg, out);
    panel2_kernel<<<SEQ / BM, CBLOCK, 0, stream>>>(x, wg, out);
    panel3_kernel<<<SEQ / BM, CBLOCK, 0, stream>>>(x, wg, bg, rm, rv, kptr, out);
}